// Round 3
// baseline (469.479 us; speedup 1.0000x reference)
//
#include <hip/hip_runtime.h>
#include <math.h>
#include <stdint.h>

#define NTOK   16384
#define DIM    4096
#define NEXP   256
#define TOPKG  4
#define TOPK   8
#define NSPLIT 4
#define KCHUNK (DIM / NSPLIT)   // 1024
#define BM     64               // small tile -> 64 AGPR acc -> 4 waves/SIMD
#define BK     32
#define NSTEPS (KCHUNK / BK)    // 32

typedef float v4f   __attribute__((ext_vector_type(4)));
typedef short short8 __attribute__((ext_vector_type(8)));

__device__ inline unsigned short f2bf(float x) {           // round-to-nearest-even
    unsigned u = __float_as_uint(x);
    return (unsigned short)((u + 0x7fffu + ((u >> 16) & 1u)) >> 16);
}
__device__ inline float bf2f(unsigned short h) {
    return __uint_as_float(((unsigned)h) << 16);
}
// 4-slot XOR swizzle within a 64B row (involution; verified R2: conflicts=0)
__device__ inline int swz4(int row, int slot) { return slot ^ ((row >> 1) & 3); }

// ---- W fp32 -> bf16 (hi, lo) row-major [256][4096], done once per call ----
__global__ __launch_bounds__(256) void wprep(const float* __restrict__ W,
                                             unsigned short* __restrict__ Wh,
                                             unsigned short* __restrict__ Wl) {
    int i = (blockIdx.x * 256 + threadIdx.x) * 4;
    float4 v = *(const float4*)(W + i);
    ushort4 h, l;
    h.x = f2bf(v.x); l.x = f2bf(v.x - bf2f(h.x));
    h.y = f2bf(v.y); l.y = f2bf(v.y - bf2f(h.y));
    h.z = f2bf(v.z); l.z = f2bf(v.z - bf2f(h.z));
    h.w = f2bf(v.w); l.w = f2bf(v.w - bf2f(h.w));
    *(ushort4*)(Wh + i) = h;
    *(ushort4*)(Wl + i) = l;
}

// ---- GEMM: P[z][t][e] = sum_{k in chunk z} X[t,k] W[e,k], bf16x2 3-pass MFMA ----
// Occupancy-first structure: BM=64, 4 waves, acc[4][4]=64 AGPR, frags loaded
// per-iteration (VGPR ~60) -> total regs <=128 -> 4 waves/SIMD. LDS 40 KB
// single-buffer -> 4 blocks/CU (160 KB exact). Cross-block stagger hides the
// 2-barrier step latency (m114 mechanism); setprio favors MFMA-phase waves.
__global__ __launch_bounds__(256, 4) void gate_gemm(const float* __restrict__ X,
                                                    const unsigned short* __restrict__ Wh,
                                                    const unsigned short* __restrict__ Wl,
                                                    float* __restrict__ P) {
    __shared__ __align__(16) unsigned short Ah[BM * BK];    // 4 KB
    __shared__ __align__(16) unsigned short Al[BM * BK];    // 4 KB
    __shared__ __align__(16) unsigned short Bh[NEXP * BK];  // 16 KB
    __shared__ __align__(16) unsigned short Bl[NEXP * BK];  // 16 KB -> 40 KB

    const int t  = threadIdx.x;            // 0..255
    // XCD-chunked swizzle (bijective, 256 = 8*32): each XCD gets 32 consecutive
    // token-tiles of the SAME z -> that z's W chunk (1 MB) stays L2-hot.
    const int bx = (blockIdx.x & 7) * 32 + (blockIdx.x >> 3);
    const int bm = bx * BM;
    const int z  = blockIdx.y;
    const int k0 = z * KCHUNK;

    const int l  = t & 63;
    const int wc = t >> 6;                 // 0..3: 64-expert column slice
    const int lm = l & 15;
    const int lq = l >> 4;                 // 16B k-slot (0..3)

    // A staging: thread t -> row t>>2 (0..63), k-slot t&3 (8 floats)
    const int ar = t >> 2;
    const int aslot = t & 3;
    const float* xrow = X + (size_t)(bm + ar) * DIM + k0 + aslot * 8;

    v4f acc[4][4] = {};

    for (int s = 0; s < NSTEPS; ++s) {
        const int kr = s * BK;

        // X loads issued BEFORE the barrier: latency overlaps barrier wait
        float4 xv0 = *(const float4*)(xrow + kr);
        float4 xv1 = *(const float4*)(xrow + kr + 4);

        __syncthreads();   // prior step's frag reads done before overwrite

        // B: bf16 h/l global->LDS, pre-swizzled SOURCE + linear dest (rule #21)
#pragma unroll
        for (int i = 0; i < 4; ++i) {
            int flat = i * 256 + t;            // 0..1023
            int e = flat >> 2, qq = flat & 3;
            const unsigned short* g = Wh + (size_t)e * DIM + k0 + kr + swz4(e, qq) * 8;
            __builtin_amdgcn_global_load_lds(
                (const __attribute__((address_space(1))) unsigned int*)g,
                (__attribute__((address_space(3))) unsigned int*)&Bh[flat * 8], 16, 0, 0);
        }
#pragma unroll
        for (int i = 0; i < 4; ++i) {
            int flat = i * 256 + t;
            int e = flat >> 2, qq = flat & 3;
            const unsigned short* g = Wl + (size_t)e * DIM + k0 + kr + swz4(e, qq) * 8;
            __builtin_amdgcn_global_load_lds(
                (const __attribute__((address_space(1))) unsigned int*)g,
                (__attribute__((address_space(3))) unsigned int*)&Bl[flat * 8], 16, 0, 0);
        }

        // A: convert fp32 -> bf16 hi/lo, one b128 write each (swizzled slot)
        {
            short8 hv, lv;
            float xf[8] = {xv0.x, xv0.y, xv0.z, xv0.w, xv1.x, xv1.y, xv1.z, xv1.w};
#pragma unroll
            for (int j = 0; j < 8; ++j) {
                unsigned short h = f2bf(xf[j]);
                hv[j] = (short)h;
                lv[j] = (short)f2bf(xf[j] - bf2f(h));
            }
            int idx = ar * BK + swz4(ar, aslot) * 8;
            *(short8*)&Ah[idx] = hv;
            *(short8*)&Al[idx] = lv;
        }

        __syncthreads();   // full drain: gl_lds + ds_writes visible

        __builtin_amdgcn_s_setprio(1);
#pragma unroll
        for (int r = 0; r < 4; ++r) {
            const int m = r * 16 + lm;
            const short8 ah = *(const short8*)&Ah[m * BK + swz4(m, lq) * 8];
            const short8 al = *(const short8*)&Al[m * BK + swz4(m, lq) * 8];
#pragma unroll
            for (int c = 0; c < 4; ++c) {
                const int e = wc * 64 + c * 16 + lm;
                const short8 bh = *(const short8*)&Bh[e * BK + swz4(e, lq) * 8];
                const short8 bl = *(const short8*)&Bl[e * BK + swz4(e, lq) * 8];
                acc[r][c] = __builtin_amdgcn_mfma_f32_16x16x32_bf16(ah, bh, acc[r][c], 0, 0, 0);
                acc[r][c] = __builtin_amdgcn_mfma_f32_16x16x32_bf16(ah, bl, acc[r][c], 0, 0, 0);
                acc[r][c] = __builtin_amdgcn_mfma_f32_16x16x32_bf16(al, bh, acc[r][c], 0, 0, 0);
            }
        }
        __builtin_amdgcn_s_setprio(0);
    }

    // epilogue: C/D layout col=lane&15, row=lq*4+reg (verified m89/m91)
    float* Pb = P + ((size_t)z * NTOK + bm) * NEXP;
#pragma unroll
    for (int r = 0; r < 4; ++r)
#pragma unroll
        for (int c = 0; c < 4; ++c)
#pragma unroll
            for (int g = 0; g < 4; ++g)
                Pb[(size_t)(r * 16 + lq * 4 + g) * NEXP + wc * 64 + c * 16 + lm] = acc[r][c][g];
}

// ---- fused reduce (4 partials, fixed order) + routing: one wave per token ----
__global__ __launch_bounds__(256) void gate_route(const float* __restrict__ P,
                                                  float* __restrict__ outw,
                                                  float* __restrict__ outi) {
    const int lane = threadIdx.x & 63;
    const int tok  = (blockIdx.x * blockDim.x + threadIdx.x) >> 6;
    if (tok >= NTOK) return;

    float l[4] = {0.f, 0.f, 0.f, 0.f};
#pragma unroll
    for (int z = 0; z < NSPLIT; ++z) {   // fixed order: deterministic across runs
        float4 v = *(const float4*)(P + ((size_t)z * NTOK + tok) * NEXP + lane * 4);
        l[0] += v.x; l[1] += v.y; l[2] += v.z; l[3] += v.w;
    }

    float lmax = fmaxf(fmaxf(l[0], l[1]), fmaxf(l[2], l[3]));
    float m = lmax;
#pragma unroll
    for (int o = 32; o; o >>= 1) m = fmaxf(m, __shfl_xor(m, o));

    float s = __expf(l[0] - m) + __expf(l[1] - m) + __expf(l[2] - m) + __expf(l[3] - m);
#pragma unroll
    for (int o = 32; o; o >>= 1) s += __shfl_xor(s, o);

    float gm = lmax;
#pragma unroll
    for (int o = 4; o; o >>= 1) gm = fmaxf(gm, __shfl_xor(gm, o));

    const int g = lane >> 3;
    int rank = 0;
#pragma unroll
    for (int gg = 0; gg < 8; ++gg) {
        float vg = __shfl(gm, gg * 8);
        rank += (vg > gm) || (vg == gm && gg < g);
    }
    const bool allowed = rank < TOPKG;

    float mv[4];
#pragma unroll
    for (int j = 0; j < 4; ++j) mv[j] = allowed ? l[j] : -INFINITY;

    float wsel = 0.0f;
    int   isel = 0;

    for (int k = 0; k < TOPK; ++k) {
        float bv = mv[0];
        int   bi = lane * 4;
        if (mv[1] > bv) { bv = mv[1]; bi = lane * 4 + 1; }
        if (mv[2] > bv) { bv = mv[2]; bi = lane * 4 + 2; }
        if (mv[3] > bv) { bv = mv[3]; bi = lane * 4 + 3; }
#pragma unroll
        for (int o = 32; o; o >>= 1) {
            float ov = __shfl_xor(bv, o);
            int   oi = __shfl_xor(bi, o);
            if (ov > bv || (ov == bv && oi < bi)) { bv = ov; bi = oi; }
        }
        if (lane == k) { wsel = __expf(bv - m) / s; isel = bi; }
        if ((bi >> 2) == lane) mv[bi & 3] = -INFINITY;
    }

    if (lane < TOPK) {
        outw[(size_t)tok * TOPK + lane] = wsel;
        outi[(size_t)tok * TOPK + lane] = (float)isel;
    }
}

extern "C" void kernel_launch(void* const* d_in, const int* in_sizes, int n_in,
                              void* d_out, int out_size, void* d_ws, size_t ws_size,
                              hipStream_t stream) {
    const float* x  = (const float*)d_in[0];   // [16384, 4096]
    const float* wt = (const float*)d_in[1];   // [256, 4096]

    // ws layout: partials [4][16384][256] f32 (64 MB) | Wh (2 MB) | Wl (2 MB)
    float* P = (float*)d_ws;
    unsigned short* Wh = (unsigned short*)((char*)d_ws + (size_t)NSPLIT * NTOK * NEXP * 4);
    unsigned short* Wl = Wh + (size_t)NEXP * DIM;

    float* outw = (float*)d_out;
    float* outi = (float*)d_out + (size_t)NTOK * TOPK;

    wprep<<<(NEXP * DIM) / (256 * 4), 256, 0, stream>>>(wt, Wh, Wl);

    dim3 ggrid(NTOK / BM, NSPLIT);   // (256, 4) = 1024 blocks, 4/CU, all resident
    gate_gemm<<<ggrid, 256, 0, stream>>>(x, Wh, Wl, P);

    gate_route<<<(NTOK * 64) / 256, 256, 0, stream>>>(P, outw, outi);
}